// Round 1
// baseline (15810.370 us; speedup 1.0000x reference)
//
#include <hip/hip_runtime.h>
#include <hip/hip_bf16.h>
#include <stdint.h>
#include <stddef.h>

// LSTM: INPUT=512, HIDDEN=1024, BATCH=64, SEQ=512.
// Persistent-kernel design:
//   - 256 WGs x 256 threads (4 waves). WG = (batch-group bg of 16 rows) x (col-group cg of 16 h-cols).
//   - Each wave holds its 16 gate-columns' weights (W_h: K=1024, W_x: K=512) permanently in VGPRs
//     as pre-packed MFMA B-fragments (48 x short8 = 192 VGPR).
//   - Per step: stage x(t) tile + h(t-1) tile into XOR-swizzled LDS, 48 MFMAs (16x16x32 bf16),
//     wave-local gate combine via shfl_xor, c kept in registers, h published as bf16 to a
//     double-buffered global buffer, per-WG tagged flag with release fence; consumers spin on
//     relaxed agent loads + acquire fence (handles cross-XCD L2 coherence).
#define ISZ   512
#define HSZ   1024
#define NBAT  64
#define SEQL  512

typedef __attribute__((ext_vector_type(8))) short  short8;   // 8 x bf16 (4 VGPR)
typedef __attribute__((ext_vector_type(4))) float  floatx4;  // MFMA accumulator

__device__ __forceinline__ unsigned short f2bf(float f){     // RNE f32 -> bf16
  unsigned int u = __float_as_uint(f);
  u += 0x7FFFu + ((u >> 16) & 1u);
  return (unsigned short)(u >> 16);
}
__device__ __forceinline__ float sigf(float x){ return 1.0f / (1.0f + __expf(-x)); }
__device__ __forceinline__ float tanh_(float x){ return 2.0f / (1.0f + __expf(-2.0f * x)) - 1.0f; }
__device__ __forceinline__ float sel4(int idx, float a0, float a1, float a2, float a3){
  float r01 = (idx & 1) ? a1 : a0;
  float r23 = (idx & 1) ? a3 : a2;
  return (idx & 2) ? r23 : r01;
}
__device__ __forceinline__ bool flag_ok(int f, int need){
  return ((((unsigned int)f) >> 16) == 0x5AFEu) && ((f & 0xFFFF) >= need);
}

// ---------------- x f32 -> bf16 (and zero the sync flags) ----------------
__global__ __launch_bounds__(256) void k_convert_x(const float* __restrict__ x,
                                                   unsigned short* __restrict__ xb,
                                                   int* __restrict__ flags){
  if (blockIdx.x == 0 && threadIdx.x < 256) flags[threadIdx.x] = 0;  // tag-invalid => pollers wait
  int i = (blockIdx.x * 256 + threadIdx.x) * 8;                      // 8192*256*8 == 64*512*512
  const float4* p = (const float4*)(x + i);
  float4 a = p[0], b = p[1];
  unsigned int w0 = (unsigned int)f2bf(a.x) | ((unsigned int)f2bf(a.y) << 16);
  unsigned int w1 = (unsigned int)f2bf(a.z) | ((unsigned int)f2bf(a.w) << 16);
  unsigned int w2 = (unsigned int)f2bf(b.x) | ((unsigned int)f2bf(b.y) << 16);
  unsigned int w3 = (unsigned int)f2bf(b.z) | ((unsigned int)f2bf(b.w) << 16);
  *(uint4*)(xb + i) = make_uint4(w0, w1, w2, w3);
}

// ---------------- pack W_h/W_x into per-(cg,wave,chunk,lane) B-fragments ----------------
// pw index = ((cg*4 + wv)*48 + ch)*64 + lane, 16 B each. ch 0..31 => W_h k=ch*32.., ch 32..47 => W_x.
// Fragment: lane holds B[k = k0 + (lane>>4)*8 + j][col n=lane&15], col n -> gate(n>>2), hcol(n&3).
__global__ __launch_bounds__(256) void k_pack_w(const float* __restrict__ Wx,
                                                const float* __restrict__ Wh,
                                                unsigned short* __restrict__ pw){
  int id = blockIdx.x * 256 + threadIdx.x;     // < 786432 = 64*4*48*64
  int lane = id & 63;
  int ch   = (id >> 6) % 48;
  int t2   = (id >> 6) / 48;                   // cg*4 + wv
  int wv = t2 & 3, cg = t2 >> 2;
  int nn = lane & 15, kgrp = lane >> 4;
  int g = nn >> 2, hcl = nn & 3;
  int colh = cg * 16 + wv * 4 + hcl;           // 0..1023
  unsigned short o[8];
  if (ch < 32){
    int k0 = ch * 32 + kgrp * 8;
#pragma unroll
    for (int j = 0; j < 8; ++j) o[j] = f2bf(Wh[(g * 1024 + k0 + j) * 1024 + colh]);
  } else {
    int k0 = (ch - 32) * 32 + kgrp * 8;
#pragma unroll
    for (int j = 0; j < 8; ++j) o[j] = f2bf(Wx[(g * 512 + k0 + j) * 1024 + colh]);
  }
  unsigned int w0 = (unsigned int)o[0] | ((unsigned int)o[1] << 16);
  unsigned int w1 = (unsigned int)o[2] | ((unsigned int)o[3] << 16);
  unsigned int w2 = (unsigned int)o[4] | ((unsigned int)o[5] << 16);
  unsigned int w3 = (unsigned int)o[6] | ((unsigned int)o[7] << 16);
  ((uint4*)pw)[id] = make_uint4(w0, w1, w2, w3);
}

// ---------------- persistent LSTM scan ----------------
__global__ __launch_bounds__(256, 1) void k_scan(const unsigned short* __restrict__ pw,
                                                 const unsigned short* __restrict__ xb,
                                                 const float* __restrict__ bias,
                                                 unsigned short* __restrict__ hg,  // [2][64][1024] bf16
                                                 int* __restrict__ flags,          // [256]
                                                 float* __restrict__ out){         // h[64][1024] ++ c[64][1024]
  __shared__ __align__(16) char lds_h[16 * 2048];        // 16 batches x 1024 bf16, XOR-swizzled
  __shared__ __align__(16) char lds_x[16 * 1024];        // 16 batches x 512 bf16, XOR-swizzled
  __shared__ __align__(16) unsigned short hout[256];     // 16 x 16 bf16 staging for h publish

  const int wg = blockIdx.x;       // 0..255
  const int bg = wg >> 6;          // batch group 0..3
  const int cg = wg & 63;          // col group 0..63
  const int tid = threadIdx.x;
  const int wv = tid >> 6;         // wave 0..3
  const int lane = tid & 63;
  const int b0 = bg * 16;

  // ---- persistent weights in registers
  short8 bh[32], bx[16];
  {
    const uint4* base = (const uint4*)pw + (cg * 4 + wv) * 48 * 64 + lane;
#pragma unroll
    for (int c = 0; c < 32; ++c) bh[c] = *(const short8*)(base + c * 64);
#pragma unroll
    for (int c = 0; c < 16; ++c) bx[c] = *(const short8*)(base + (32 + c) * 64);
  }

  const int nn = lane & 15;        // MFMA col index n
  const int G  = nn >> 2;          // my gate group (0=i,1=f,2=g,3=o)
  const int hc = nn & 3;           // h-col within wave
  const int kgrp = lane >> 4;      // k-group 0..3
  const int colh = cg * 16 + wv * 4 + hc;    // global h-col 0..1023
  const float b_i = bias[0 * HSZ + colh];
  const float b_f = bias[1 * HSZ + colh];
  const float b_g = bias[2 * HSZ + colh];
  const float b_o = bias[3 * HSZ + colh];

  // A-fragment LDS read bases (two bases so chunk offset is a clean +q*128 immediate)
  const int arow = nn;                        // batch row 0..15
  const int swz  = (arow & 7) << 4;
  const int hb0  = arow * 2048 + ((kgrp * 16 +  0) ^ swz);
  const int hb1  = arow * 2048 + ((kgrp * 16 + 64) ^ swz);
  const int xq0  = arow * 1024 + ((kgrp * 16 +  0) ^ swz);
  const int xq1  = arow * 1024 + ((kgrp * 16 + 64) ^ swz);

  float cst[4] = {0.f, 0.f, 0.f, 0.f};        // c-state: 4 batches (rows kgrp*4+r), col hc

#pragma unroll 1
  for (int t = 0; t < SEQL; ++t){
    // ---- stage x(t): 16 rows x 1024 B, issued before the flag wait (independent of it)
    uint4 xr[4]; int xdst[4];
#pragma unroll
    for (int i = 0; i < 4; ++i){
      int ch = i * 256 + tid;                 // 0..1023
      int row = ch >> 6, o16 = ch & 63;
      xr[i] = *(const uint4*)((const char*)xb + (((size_t)(b0 + row) * SEQL + t) * ISZ) * 2 + o16 * 16);
      xdst[i] = row * 1024 + ((o16 * 16) ^ ((row & 7) << 4));
    }

    // ---- wait for all WGs to have published h(t-1)
    if (t > 0){
      if (wv == 0){
        int need = t;
        for (;;){
          int f0 = __hip_atomic_load(&flags[lane * 4 + 0], __ATOMIC_RELAXED, __HIP_MEMORY_SCOPE_AGENT);
          int f1 = __hip_atomic_load(&flags[lane * 4 + 1], __ATOMIC_RELAXED, __HIP_MEMORY_SCOPE_AGENT);
          int f2 = __hip_atomic_load(&flags[lane * 4 + 2], __ATOMIC_RELAXED, __HIP_MEMORY_SCOPE_AGENT);
          int f3 = __hip_atomic_load(&flags[lane * 4 + 3], __ATOMIC_RELAXED, __HIP_MEMORY_SCOPE_AGENT);
          bool ok = flag_ok(f0, need) && flag_ok(f1, need) && flag_ok(f2, need) && flag_ok(f3, need);
          if (__all((int)ok)) break;
          __builtin_amdgcn_s_sleep(1);
        }
      }
      __syncthreads();
      __threadfence();   // acquire: invalidate stale L2 before reading h from other XCDs
    }

    // ---- stage h(t-1): 16 rows x 2048 B (garbage at t==0; unused then)
    uint4 hr[8]; int hdst[8];
    const int par_r = (t - 1) & 1;
#pragma unroll
    for (int i = 0; i < 8; ++i){
      int ch = i * 256 + tid;                 // 0..2047
      int row = ch >> 7, o16 = ch & 127;
      hr[i] = *(const uint4*)((const char*)hg + ((size_t)(par_r * 64 + b0 + row) * 1024) * 2 + o16 * 16);
      hdst[i] = row * 2048 + ((o16 * 16) ^ ((row & 7) << 4));
    }
#pragma unroll
    for (int i = 0; i < 4; ++i) *(uint4*)(lds_x + xdst[i]) = xr[i];
#pragma unroll
    for (int i = 0; i < 8; ++i) *(uint4*)(lds_h + hdst[i]) = hr[i];
    __syncthreads();

    // ---- gates GEMM: acc[b 0..15][n 0..15] over K=1024 (h) + 512 (x); two accs shorten dep chain
    floatx4 acc0 = {0.f, 0.f, 0.f, 0.f};
    floatx4 acc1 = {0.f, 0.f, 0.f, 0.f};
    if (t > 0){
#pragma unroll
      for (int q = 0; q < 16; ++q){
        short8 a0 = *(const short8*)(lds_h + hb0 + q * 128);
        acc0 = __builtin_amdgcn_mfma_f32_16x16x32_bf16(a0, bh[2 * q], acc0, 0, 0, 0);
        short8 a1 = *(const short8*)(lds_h + hb1 + q * 128);
        acc1 = __builtin_amdgcn_mfma_f32_16x16x32_bf16(a1, bh[2 * q + 1], acc1, 0, 0, 0);
      }
    }
#pragma unroll
    for (int q = 0; q < 8; ++q){
      short8 a0 = *(const short8*)(lds_x + xq0 + q * 128);
      acc0 = __builtin_amdgcn_mfma_f32_16x16x32_bf16(a0, bx[2 * q], acc0, 0, 0, 0);
      short8 a1 = *(const short8*)(lds_x + xq1 + q * 128);
      acc1 = __builtin_amdgcn_mfma_f32_16x16x32_bf16(a1, bx[2 * q + 1], acc1, 0, 0, 0);
    }

    // ---- elementwise: combine i/f/g/o (live in lane-groups differing in bits 2..3 of lane)
#pragma unroll
    for (int r = 0; r < 4; ++r){
      float own = acc0[r] + acc1[r];
      float s4  = __shfl_xor(own, 4);
      float s8  = __shfl_xor(own, 8);
      float s12 = __shfl_xor(own, 12);
      float pi = sel4(G,     own, s4, s8, s12) + b_i;
      float pf = sel4(G ^ 1, own, s4, s8, s12) + b_f;
      float pg = sel4(G ^ 2, own, s4, s8, s12) + b_g;
      float po = sel4(G ^ 3, own, s4, s8, s12) + b_o;
      float iv = sigf(pi), fv = sigf(pf), gv = tanh_(pg), ov = sigf(po);
      float cn = fv * cst[r] + iv * gv;
      cst[r] = cn;
      float hv = ov * tanh_(cn);
      if (G == 0){
        int brow = kgrp * 4 + r;                       // batch row 0..15
        hout[brow * 16 + wv * 4 + hc] = f2bf(hv);
        if (t == SEQL - 1){
          int gb = b0 + brow;
          out[gb * HSZ + colh] = hv;                   // h_T
          out[NBAT * HSZ + gb * HSZ + colh] = cn;      // c_T
        }
      }
    }
    __syncthreads();

    // ---- publish h(t) + release flag
    if (wv == 0){
      if (lane < 32){
        int row = lane >> 1, half = lane & 1;
        uint4 v = *(const uint4*)((const char*)hout + row * 32 + half * 16);
        *(uint4*)((char*)hg + ((size_t)((t & 1) * 64 + b0 + row) * 1024 + cg * 16 + half * 8) * 2) = v;
      }
      __threadfence();   // release: write back dirty L2 to coherence point
      if (lane == 0)
        __hip_atomic_store(&flags[wg], (int)(0x5AFE0000u | (unsigned)(t + 1)),
                           __ATOMIC_RELAXED, __HIP_MEMORY_SCOPE_AGENT);
    }
  }
}

extern "C" void kernel_launch(void* const* d_in, const int* in_sizes, int n_in,
                              void* d_out, int out_size, void* d_ws, size_t ws_size,
                              hipStream_t stream){
  (void)in_sizes; (void)n_in; (void)out_size; (void)ws_size;
  const float* x  = (const float*)d_in[0];   // [64][512][512]
  const float* Wx = (const float*)d_in[1];   // [4][512][1024]
  const float* Wh = (const float*)d_in[2];   // [4][1024][1024]
  const float* b  = (const float*)d_in[3];   // [4][1024]
  char* ws = (char*)d_ws;
  unsigned short* pw    = (unsigned short*)ws;                    // 12,582,912 B packed weights
  unsigned short* xbf   = (unsigned short*)(ws + 12582912);       // 33,554,432 B x in bf16
  unsigned short* hg    = (unsigned short*)(ws + 46137344);       //    262,144 B h double buffer
  int*            flags = (int*)(ws + 46399488);                  //      1,024 B sync flags
  float* out = (float*)d_out;

  k_convert_x<<<dim3(8192), dim3(256), 0, stream>>>(x, xbf, flags);
  k_pack_w  <<<dim3(3072), dim3(256), 0, stream>>>(Wx, Wh, pw);
  k_scan    <<<dim3(256),  dim3(256), 0, stream>>>(pw, xbf, b, hg, flags, out);
}

// Round 2
// 8354.266 us; speedup vs baseline: 1.8925x; 1.8925x over previous
//
#include <hip/hip_runtime.h>
#include <hip/hip_bf16.h>
#include <stdint.h>
#include <stddef.h>

// LSTM: INPUT=512, HIDDEN=1024, BATCH=64, SEQ=512.
// Persistent-kernel, fence-free dataflow sync:
//   - 256 WGs x 256 threads. WG = (batch-group bg: 16 rows) x (col-group cg: 16 h-cols).
//   - Weights live in registers (48 x short8 B-fragments per wave).
//   - Cross-WG h exchange via agent-scope (sc1) atomic loads/stores -> MALL coherence point.
//     NO __threadfence (no buffer_inv L2 nukes). Flags are per-WG monotonic counters,
//     bumped once per wave with a RELEASE fetch_add (s_waitcnt vmcnt(0) + atomic only).
//   - 4 bg-groups are independent chains; each WG polls only its own 64 producers.
#define ISZ   512
#define HSZ   1024
#define NBAT  64
#define SEQL  512

typedef __attribute__((ext_vector_type(8))) short  short8;   // 8 x bf16 (4 VGPR)
typedef __attribute__((ext_vector_type(4))) float  floatx4;  // MFMA accumulator

__device__ __forceinline__ unsigned short f2bf(float f){     // RNE f32 -> bf16
  unsigned int u = __float_as_uint(f);
  u += 0x7FFFu + ((u >> 16) & 1u);
  return (unsigned short)(u >> 16);
}
__device__ __forceinline__ float sigf(float x){ return 1.0f / (1.0f + __expf(-x)); }
__device__ __forceinline__ float tanh_(float x){ return 2.0f / (1.0f + __expf(-2.0f * x)) - 1.0f; }
__device__ __forceinline__ float sel4(int idx, float a0, float a1, float a2, float a3){
  float r01 = (idx & 1) ? a1 : a0;
  float r23 = (idx & 1) ? a3 : a2;
  return (idx & 2) ? r23 : r01;
}

// ---------------- x f32 -> bf16 (and zero the sync flag counters) ----------------
__global__ __launch_bounds__(256) void k_convert_x(const float* __restrict__ x,
                                                   unsigned short* __restrict__ xb,
                                                   int* __restrict__ flags){
  if (blockIdx.x == 0 && threadIdx.x < 256) flags[threadIdx.x] = 0;
  int i = (blockIdx.x * 256 + threadIdx.x) * 8;                      // 8192*256*8 == 64*512*512
  const float4* p = (const float4*)(x + i);
  float4 a = p[0], b = p[1];
  unsigned int w0 = (unsigned int)f2bf(a.x) | ((unsigned int)f2bf(a.y) << 16);
  unsigned int w1 = (unsigned int)f2bf(a.z) | ((unsigned int)f2bf(a.w) << 16);
  unsigned int w2 = (unsigned int)f2bf(b.x) | ((unsigned int)f2bf(b.y) << 16);
  unsigned int w3 = (unsigned int)f2bf(b.z) | ((unsigned int)f2bf(b.w) << 16);
  *(uint4*)(xb + i) = make_uint4(w0, w1, w2, w3);
}

// ---------------- pack W_h/W_x into per-(cg,wave,chunk,lane) B-fragments ----------------
__global__ __launch_bounds__(256) void k_pack_w(const float* __restrict__ Wx,
                                                const float* __restrict__ Wh,
                                                unsigned short* __restrict__ pw){
  int id = blockIdx.x * 256 + threadIdx.x;     // < 786432 = 64*4*48*64
  int lane = id & 63;
  int ch   = (id >> 6) % 48;
  int t2   = (id >> 6) / 48;                   // cg*4 + wv
  int wv = t2 & 3, cg = t2 >> 2;
  int nn = lane & 15, kgrp = lane >> 4;
  int g = nn >> 2, hcl = nn & 3;
  int colh = cg * 16 + wv * 4 + hcl;           // 0..1023
  unsigned short o[8];
  if (ch < 32){
    int k0 = ch * 32 + kgrp * 8;
#pragma unroll
    for (int j = 0; j < 8; ++j) o[j] = f2bf(Wh[(g * 1024 + k0 + j) * 1024 + colh]);
  } else {
    int k0 = (ch - 32) * 32 + kgrp * 8;
#pragma unroll
    for (int j = 0; j < 8; ++j) o[j] = f2bf(Wx[(g * 512 + k0 + j) * 1024 + colh]);
  }
  unsigned int w0 = (unsigned int)o[0] | ((unsigned int)o[1] << 16);
  unsigned int w1 = (unsigned int)o[2] | ((unsigned int)o[3] << 16);
  unsigned int w2 = (unsigned int)o[4] | ((unsigned int)o[5] << 16);
  unsigned int w3 = (unsigned int)o[6] | ((unsigned int)o[7] << 16);
  ((uint4*)pw)[id] = make_uint4(w0, w1, w2, w3);
}

// ---------------- persistent LSTM scan ----------------
__global__ __launch_bounds__(256, 1) void k_scan(const unsigned short* __restrict__ pw,
                                                 const unsigned short* __restrict__ xb,
                                                 const float* __restrict__ bias,
                                                 unsigned long long* __restrict__ hgq, // [2][64][1024] bf16 as qwords
                                                 int* __restrict__ flags,              // [256] counters
                                                 float* __restrict__ out){             // h[64][1024] ++ c[64][1024]
  __shared__ __align__(16) char lds_h[16 * 2048];        // 16 batches x 1024 bf16, XOR-swizzled
  __shared__ __align__(16) char lds_x[16 * 1024];        // 16 batches x 512 bf16, XOR-swizzled

  const int wg = blockIdx.x;       // 0..255
  const int bg = wg >> 6;          // batch group 0..3 (independent chains)
  const int cg = wg & 63;          // col group 0..63
  const int tid = threadIdx.x;
  const int wv = tid >> 6;         // wave 0..3
  const int lane = tid & 63;
  const int b0 = bg * 16;

  // ---- persistent weights in registers
  short8 bh[32], bx[16];
  {
    const uint4* base = (const uint4*)pw + (cg * 4 + wv) * 48 * 64 + lane;
#pragma unroll
    for (int c = 0; c < 32; ++c) bh[c] = *(const short8*)(base + c * 64);
#pragma unroll
    for (int c = 0; c < 16; ++c) bx[c] = *(const short8*)(base + (32 + c) * 64);
  }

  const int nn = lane & 15;        // MFMA col index n
  const int G  = nn >> 2;          // gate group (0=i,1=f,2=g,3=o)
  const int hc = nn & 3;           // h-col within wave
  const int kgrp = lane >> 4;      // k-group 0..3
  const int colh = cg * 16 + wv * 4 + hc;    // global h-col 0..1023
  const float b_i = bias[0 * HSZ + colh];
  const float b_f = bias[1 * HSZ + colh];
  const float b_g = bias[2 * HSZ + colh];
  const float b_o = bias[3 * HSZ + colh];

  // A-fragment LDS read bases
  const int arow = nn;                        // batch row 0..15
  const int swz  = (arow & 7) << 4;
  const int hb0  = arow * 2048 + ((kgrp * 16 +  0) ^ swz);
  const int hb1  = arow * 2048 + ((kgrp * 16 + 64) ^ swz);
  const int xq0  = arow * 1024 + ((kgrp * 16 +  0) ^ swz);
  const int xq1  = arow * 1024 + ((kgrp * 16 + 64) ^ swz);

  float cst[4] = {0.f, 0.f, 0.f, 0.f};        // c-state: rows kgrp*4+r, col hc

#pragma unroll 1
  for (int t = 0; t < SEQL; ++t){
    // ---- stage x(t): issued before the flag wait (independent of it); normal (L2-cached) loads
    uint4 xr[4]; int xdst[4];
#pragma unroll
    for (int i = 0; i < 4; ++i){
      int ch = i * 256 + tid;                 // 0..1023
      int row = ch >> 6, o16 = ch & 63;
      xr[i] = *(const uint4*)((const char*)xb + (((size_t)(b0 + row) * SEQL + t) * ISZ) * 2 + o16 * 16);
      xdst[i] = row * 1024 + ((o16 * 16) ^ ((row & 7) << 4));
    }

    // ---- wait for my 64 producers (same bg) to have published h(t-1): 4 waves each
    if (t > 0){
      if (wv == 0){
        const int need = 4 * t;
        const int fidx = bg * 64 + lane;
        for (;;){
          int f = __hip_atomic_load(&flags[fidx], __ATOMIC_RELAXED, __HIP_MEMORY_SCOPE_AGENT);
          if (__all(f >= need)) break;
          __builtin_amdgcn_s_sleep(1);
        }
      }
      __syncthreads();   // barrier A: also separates prev-step LDS reads from this step's writes
    }

    // ---- stage h(t-1): agent-scope (sc1) loads -> read MALL, immune to stale L2
    if (t > 0){
      unsigned long long hr[16]; int hdst[16];
      const int par_r = (t - 1) & 1;
#pragma unroll
      for (int i = 0; i < 16; ++i){
        int ch = i * 256 + tid;               // 0..4095 qword chunks
        int row = ch >> 8, o8 = ch & 255;
        hr[i] = __hip_atomic_load(hgq + ((size_t)(par_r * 64 + b0 + row)) * 256 + o8,
                                  __ATOMIC_RELAXED, __HIP_MEMORY_SCOPE_AGENT);
        hdst[i] = row * 2048 + ((o8 * 8) ^ ((row & 7) << 4));
      }
#pragma unroll
      for (int i = 0; i < 16; ++i) *(unsigned long long*)(lds_h + hdst[i]) = hr[i];
    }
#pragma unroll
    for (int i = 0; i < 4; ++i) *(uint4*)(lds_x + xdst[i]) = xr[i];
    __syncthreads();     // barrier B: LDS writes -> reads

    // ---- gates GEMM: K=1024 (h) + 512 (x); two accumulators
    floatx4 acc0 = {0.f, 0.f, 0.f, 0.f};
    floatx4 acc1 = {0.f, 0.f, 0.f, 0.f};
    if (t > 0){
#pragma unroll
      for (int q = 0; q < 16; ++q){
        short8 a0 = *(const short8*)(lds_h + hb0 + q * 128);
        acc0 = __builtin_amdgcn_mfma_f32_16x16x32_bf16(a0, bh[2 * q], acc0, 0, 0, 0);
        short8 a1 = *(const short8*)(lds_h + hb1 + q * 128);
        acc1 = __builtin_amdgcn_mfma_f32_16x16x32_bf16(a1, bh[2 * q + 1], acc1, 0, 0, 0);
      }
    }
#pragma unroll
    for (int q = 0; q < 8; ++q){
      short8 a0 = *(const short8*)(lds_x + xq0 + q * 128);
      acc0 = __builtin_amdgcn_mfma_f32_16x16x32_bf16(a0, bx[2 * q], acc0, 0, 0, 0);
      short8 a1 = *(const short8*)(lds_x + xq1 + q * 128);
      acc1 = __builtin_amdgcn_mfma_f32_16x16x32_bf16(a1, bx[2 * q + 1], acc1, 0, 0, 0);
    }

    // ---- elementwise combine (gate partials live in lane-groups differing in lane bits 2..3)
    float hvv[4];
#pragma unroll
    for (int r = 0; r < 4; ++r){
      float own = acc0[r] + acc1[r];
      float s4  = __shfl_xor(own, 4);
      float s8  = __shfl_xor(own, 8);
      float s12 = __shfl_xor(own, 12);
      float pi = sel4(G,     own, s4, s8, s12) + b_i;
      float pf = sel4(G ^ 1, own, s4, s8, s12) + b_f;
      float pg = sel4(G ^ 2, own, s4, s8, s12) + b_g;
      float po = sel4(G ^ 3, own, s4, s8, s12) + b_o;
      float iv = sigf(pi), fv = sigf(pf), gv = tanh_(pg), ov = sigf(po);
      float cn = fv * cst[r] + iv * gv;
      cst[r] = cn;
      hvv[r] = ov * tanh_(cn);
      if (G == 0 && t == SEQL - 1){
        int gb = b0 + kgrp * 4 + r;
        out[gb * HSZ + colh] = hvv[r];                 // h_T
        out[NBAT * HSZ + gb * HSZ + colh] = cn;        // c_T
      }
    }

    // ---- publish h(t): 4x4 shfl transpose within (kgrp, nn=0..3) group, then 8-B agent stores
    if (G == 0){
      float a0 = hvv[0], a1 = hvv[1], a2 = hvv[2], a3 = hvv[3];
      // stage mask 1: a[e] = ((nn^e)&1) ? shfl_xor(a[e^1],1) : a[e]
      float s0 = __shfl_xor(a1, 1), s1 = __shfl_xor(a0, 1);
      float s2 = __shfl_xor(a3, 1), s3 = __shfl_xor(a2, 1);
      bool o1 = (nn & 1);
      float t0 = o1 ? s0 : a0,  t1 = o1 ? a1 : s1;
      float t2 = o1 ? s2 : a2,  t3 = o1 ? a3 : s3;
      // stage mask 2
      float u0 = __shfl_xor(t2, 2), u1 = __shfl_xor(t3, 2);
      float u2 = __shfl_xor(t0, 2), u3 = __shfl_xor(t1, 2);
      bool o2 = (nn & 2);
      float w0 = o2 ? u0 : t0,  w1 = o2 ? u1 : t1;
      float w2 = o2 ? t2 : u2,  w3 = o2 ? t3 : u3;
      // lane nn now holds row kgrp*4+nn, cols (cg*16+wv*4)+0..3
      unsigned int lo = (unsigned int)f2bf(w0) | ((unsigned int)f2bf(w1) << 16);
      unsigned int hi = (unsigned int)f2bf(w2) | ((unsigned int)f2bf(w3) << 16);
      unsigned long long v = ((unsigned long long)hi << 32) | lo;
      int row = kgrp * 4 + nn;
      __hip_atomic_store(hgq + ((size_t)((t & 1) * 64 + b0 + row)) * 256 + (cg * 4 + wv), v,
                         __ATOMIC_RELAXED, __HIP_MEMORY_SCOPE_AGENT);
    }
    // ---- per-wave release: s_waitcnt vmcnt(0) + atomic add (no cache maintenance)
    if (lane == 0)
      __hip_atomic_fetch_add(&flags[wg], 1, __ATOMIC_RELEASE, __HIP_MEMORY_SCOPE_AGENT);
  }
}

extern "C" void kernel_launch(void* const* d_in, const int* in_sizes, int n_in,
                              void* d_out, int out_size, void* d_ws, size_t ws_size,
                              hipStream_t stream){
  (void)in_sizes; (void)n_in; (void)out_size; (void)ws_size;
  const float* x  = (const float*)d_in[0];   // [64][512][512]
  const float* Wx = (const float*)d_in[1];   // [4][512][1024]
  const float* Wh = (const float*)d_in[2];   // [4][1024][1024]
  const float* b  = (const float*)d_in[3];   // [4][1024]
  char* ws = (char*)d_ws;
  unsigned short* pw    = (unsigned short*)ws;                    // 12,582,912 B packed weights
  unsigned short* xbf   = (unsigned short*)(ws + 12582912);       // 33,554,432 B x in bf16
  unsigned long long* hg= (unsigned long long*)(ws + 46137344);   //    262,144 B h double buffer
  int*            flags = (int*)(ws + 46399488);                  //      1,024 B sync counters
  float* out = (float*)d_out;

  k_convert_x<<<dim3(8192), dim3(256), 0, stream>>>(x, xbf, flags);
  k_pack_w  <<<dim3(3072), dim3(256), 0, stream>>>(Wx, Wh, pw);
  k_scan    <<<dim3(256),  dim3(256), 0, stream>>>(pw, xbf, b, (unsigned long long*)hg, flags, out);
}

// Round 3
// 3157.270 us; speedup vs baseline: 5.0076x; 2.6460x over previous
//
#include <hip/hip_runtime.h>
#include <hip/hip_bf16.h>
#include <stdint.h>
#include <stddef.h>

// LSTM: INPUT=512, HIDDEN=1024, BATCH=64, SEQ=512.
// Persistent-kernel, fence-free dataflow sync, weights PINNED in VGPRs.
//   - 256 WGs x 256 threads. WG = (batch-group bg: 16 rows) x (col-group cg: 16 h-cols).
//   - Each wave owns 16 gate-columns x K=1536 as 48 short8 B-fragments, held in registers
//     (inline-asm pinned so regalloc cannot sink the loads into the step loop).
//   - Cross-WG h exchange via agent-scope (sc1) loads/stores -> MALL coherence point.
//   - Flags: per-WG monotonic counters; publish = stores + explicit vmcnt(0) + relaxed add.
#define ISZ   512
#define HSZ   1024
#define NBAT  64
#define SEQL  512

typedef __attribute__((ext_vector_type(8))) short  short8;   // 8 x bf16 (4 VGPR)
typedef __attribute__((ext_vector_type(4))) float  floatx4;  // MFMA accumulator

__device__ __forceinline__ unsigned short f2bf(float f){     // RNE f32 -> bf16
  unsigned int u = __float_as_uint(f);
  u += 0x7FFFu + ((u >> 16) & 1u);
  return (unsigned short)(u >> 16);
}
__device__ __forceinline__ float sigf(float x){ return 1.0f / (1.0f + __expf(-x)); }
__device__ __forceinline__ float tanh_(float x){ return 2.0f / (1.0f + __expf(-2.0f * x)) - 1.0f; }
__device__ __forceinline__ float sel4(int idx, float a0, float a1, float a2, float a3){
  float r01 = (idx & 1) ? a1 : a0;
  float r23 = (idx & 1) ? a3 : a2;
  return (idx & 2) ? r23 : r01;
}

// ---------------- x f32 -> bf16 (and zero the sync flag counters) ----------------
__global__ __launch_bounds__(256) void k_convert_x(const float* __restrict__ x,
                                                   unsigned short* __restrict__ xb,
                                                   int* __restrict__ flags){
  if (blockIdx.x == 0 && threadIdx.x < 256) flags[threadIdx.x] = 0;
  int i = (blockIdx.x * 256 + threadIdx.x) * 8;                      // 8192*256*8 == 64*512*512
  const float4* p = (const float4*)(x + i);
  float4 a = p[0], b = p[1];
  unsigned int w0 = (unsigned int)f2bf(a.x) | ((unsigned int)f2bf(a.y) << 16);
  unsigned int w1 = (unsigned int)f2bf(a.z) | ((unsigned int)f2bf(a.w) << 16);
  unsigned int w2 = (unsigned int)f2bf(b.x) | ((unsigned int)f2bf(b.y) << 16);
  unsigned int w3 = (unsigned int)f2bf(b.z) | ((unsigned int)f2bf(b.w) << 16);
  *(uint4*)(xb + i) = make_uint4(w0, w1, w2, w3);
}

// ---------------- pack W_h/W_x into per-(cg,wave,chunk,lane) B-fragments ----------------
__global__ __launch_bounds__(256) void k_pack_w(const float* __restrict__ Wx,
                                                const float* __restrict__ Wh,
                                                unsigned short* __restrict__ pw){
  int id = blockIdx.x * 256 + threadIdx.x;     // < 786432 = 64*4*48*64
  int lane = id & 63;
  int ch   = (id >> 6) % 48;
  int t2   = (id >> 6) / 48;                   // cg*4 + wv
  int wv = t2 & 3, cg = t2 >> 2;
  int nn = lane & 15, kgrp = lane >> 4;
  int g = nn >> 2, hcl = nn & 3;
  int colh = cg * 16 + wv * 4 + hcl;           // 0..1023
  unsigned short o[8];
  if (ch < 32){
    int k0 = ch * 32 + kgrp * 8;
#pragma unroll
    for (int j = 0; j < 8; ++j) o[j] = f2bf(Wh[(g * 1024 + k0 + j) * 1024 + colh]);
  } else {
    int k0 = (ch - 32) * 32 + kgrp * 8;
#pragma unroll
    for (int j = 0; j < 8; ++j) o[j] = f2bf(Wx[(g * 512 + k0 + j) * 1024 + colh]);
  }
  unsigned int w0 = (unsigned int)o[0] | ((unsigned int)o[1] << 16);
  unsigned int w1 = (unsigned int)o[2] | ((unsigned int)o[3] << 16);
  unsigned int w2 = (unsigned int)o[4] | ((unsigned int)o[5] << 16);
  unsigned int w3 = (unsigned int)o[6] | ((unsigned int)o[7] << 16);
  ((uint4*)pw)[id] = make_uint4(w0, w1, w2, w3);
}

// ---------------- persistent LSTM scan ----------------
__global__ __launch_bounds__(256, 1) void k_scan(const unsigned short* __restrict__ pw,
                                                 const unsigned short* __restrict__ xb,
                                                 const float* __restrict__ bias,
                                                 unsigned long long* __restrict__ hgq, // [2][64][1024] bf16 as qwords
                                                 int* __restrict__ flags,              // [256] counters
                                                 float* __restrict__ out){             // h[64][1024] ++ c[64][1024]
  __shared__ __align__(16) char lds_h[16 * 2048];        // 16 batches x 1024 bf16, XOR-swizzled
  __shared__ __align__(16) char lds_x[16 * 1024];        // 16 batches x 512 bf16, XOR-swizzled

  const int wg = blockIdx.x;       // 0..255
  const int bg = wg >> 6;          // batch group 0..3 (independent chains)
  const int cg = wg & 63;          // col group 0..63
  const int tid = threadIdx.x;
  const int wv = tid >> 6;         // wave 0..3
  const int lane = tid & 63;
  const int b0 = bg * 16;

  // ---- persistent weights in registers, PINNED so regalloc can't sink the loads
  short8 bh[32], bx[16];
  {
    const uint4* base = (const uint4*)pw + (cg * 4 + wv) * 48 * 64 + lane;
#pragma unroll
    for (int c = 0; c < 32; ++c) bh[c] = *(const short8*)(base + c * 64);
#pragma unroll
    for (int c = 0; c < 16; ++c) bx[c] = *(const short8*)(base + (32 + c) * 64);
  }
#pragma unroll
  for (int c = 0; c < 32; ++c) asm volatile("" : "+v"(bh[c]));
#pragma unroll
  for (int c = 0; c < 16; ++c) asm volatile("" : "+v"(bx[c]));

  const int nn = lane & 15;        // MFMA col index n
  const int G  = nn >> 2;          // gate group (0=i,1=f,2=g,3=o)
  const int hc = nn & 3;           // h-col within wave
  const int kgrp = lane >> 4;      // k-group 0..3
  const int colh = cg * 16 + wv * 4 + hc;    // global h-col 0..1023
  const float b_i = bias[0 * HSZ + colh];
  const float b_f = bias[1 * HSZ + colh];
  const float b_g = bias[2 * HSZ + colh];
  const float b_o = bias[3 * HSZ + colh];

  // A-fragment LDS read bases
  const int arow = nn;                        // batch row 0..15
  const int swz  = (arow & 7) << 4;
  const int hb0  = arow * 2048 + ((kgrp * 16 +  0) ^ swz);
  const int hb1  = arow * 2048 + ((kgrp * 16 + 64) ^ swz);
  const int xq0  = arow * 1024 + ((kgrp * 16 +  0) ^ swz);
  const int xq1  = arow * 1024 + ((kgrp * 16 + 64) ^ swz);

  float cst[4] = {0.f, 0.f, 0.f, 0.f};        // c-state: rows kgrp*4+r, col hc

#pragma unroll 1
  for (int t = 0; t < SEQL; ++t){
    // ---- stage x(t): issued before the flag wait (independent of it); normal (L2-cached) loads
    uint4 xr[4]; int xdst[4];
#pragma unroll
    for (int i = 0; i < 4; ++i){
      int ch = i * 256 + tid;                 // 0..1023
      int row = ch >> 6, o16 = ch & 63;
      xr[i] = *(const uint4*)((const char*)xb + (((size_t)(b0 + row) * SEQL + t) * ISZ) * 2 + o16 * 16);
      xdst[i] = row * 1024 + ((o16 * 16) ^ ((row & 7) << 4));
    }

    // ---- wait for my 64 producers (same bg) to have published h(t-1): 4 waves each
    if (t > 0){
      if (wv == 0){
        const int need = 4 * t;
        const int fidx = bg * 64 + lane;
        for (;;){
          int f = __hip_atomic_load(&flags[fidx], __ATOMIC_RELAXED, __HIP_MEMORY_SCOPE_AGENT);
          if (__all(f >= need)) break;
          __builtin_amdgcn_s_sleep(1);
        }
      }
      __syncthreads();   // barrier A: also separates prev-step LDS reads from this step's writes
    }

    // ---- stage h(t-1): agent-scope (sc1) loads -> read MALL, immune to stale L2
    if (t > 0){
      unsigned long long hr[16]; int hdst[16];
      const int par_r = (t - 1) & 1;
#pragma unroll
      for (int i = 0; i < 16; ++i){
        int ch = i * 256 + tid;               // 0..4095 qword chunks
        int row = ch >> 8, o8 = ch & 255;
        hr[i] = __hip_atomic_load(hgq + ((size_t)(par_r * 64 + b0 + row)) * 256 + o8,
                                  __ATOMIC_RELAXED, __HIP_MEMORY_SCOPE_AGENT);
        hdst[i] = row * 2048 + ((o8 * 8) ^ ((row & 7) << 4));
      }
#pragma unroll
      for (int i = 0; i < 16; ++i) *(unsigned long long*)(lds_h + hdst[i]) = hr[i];
    }
#pragma unroll
    for (int i = 0; i < 4; ++i) *(uint4*)(lds_x + xdst[i]) = xr[i];
    __syncthreads();     // barrier B: LDS writes -> reads

    // ---- gates GEMM: K=1024 (h) + 512 (x); two accumulators
    floatx4 acc0 = {0.f, 0.f, 0.f, 0.f};
    floatx4 acc1 = {0.f, 0.f, 0.f, 0.f};
    if (t > 0){
#pragma unroll
      for (int q = 0; q < 16; ++q){
        short8 a0 = *(const short8*)(lds_h + hb0 + q * 128);
        acc0 = __builtin_amdgcn_mfma_f32_16x16x32_bf16(a0, bh[2 * q], acc0, 0, 0, 0);
        short8 a1 = *(const short8*)(lds_h + hb1 + q * 128);
        acc1 = __builtin_amdgcn_mfma_f32_16x16x32_bf16(a1, bh[2 * q + 1], acc1, 0, 0, 0);
      }
    }
#pragma unroll
    for (int q = 0; q < 8; ++q){
      short8 a0 = *(const short8*)(lds_x + xq0 + q * 128);
      acc0 = __builtin_amdgcn_mfma_f32_16x16x32_bf16(a0, bx[2 * q], acc0, 0, 0, 0);
      short8 a1 = *(const short8*)(lds_x + xq1 + q * 128);
      acc1 = __builtin_amdgcn_mfma_f32_16x16x32_bf16(a1, bx[2 * q + 1], acc1, 0, 0, 0);
    }

    // ---- elementwise combine (gate partials live in lane-groups differing in lane bits 2..3)
    float hvv[4];
#pragma unroll
    for (int r = 0; r < 4; ++r){
      float own = acc0[r] + acc1[r];
      float s4  = __shfl_xor(own, 4);
      float s8  = __shfl_xor(own, 8);
      float s12 = __shfl_xor(own, 12);
      float pi = sel4(G,     own, s4, s8, s12) + b_i;
      float pf = sel4(G ^ 1, own, s4, s8, s12) + b_f;
      float pg = sel4(G ^ 2, own, s4, s8, s12) + b_g;
      float po = sel4(G ^ 3, own, s4, s8, s12) + b_o;
      float iv = sigf(pi), fv = sigf(pf), gv = tanh_(pg), ov = sigf(po);
      float cn = fv * cst[r] + iv * gv;
      cst[r] = cn;
      hvv[r] = ov * tanh_(cn);
      if (G == 0 && t == SEQL - 1){
        int gb = b0 + kgrp * 4 + r;
        out[gb * HSZ + colh] = hvv[r];                 // h_T
        out[NBAT * HSZ + gb * HSZ + colh] = cn;        // c_T
      }
    }

    // ---- publish h(t): 4x4 shfl transpose within (kgrp, nn=0..3) group, then 8-B agent stores
    if (G == 0){
      float a0 = hvv[0], a1 = hvv[1], a2 = hvv[2], a3 = hvv[3];
      float s0 = __shfl_xor(a1, 1), s1 = __shfl_xor(a0, 1);
      float s2 = __shfl_xor(a3, 1), s3 = __shfl_xor(a2, 1);
      bool o1 = (nn & 1);
      float t0 = o1 ? s0 : a0,  t1 = o1 ? a1 : s1;
      float t2 = o1 ? s2 : a2,  t3 = o1 ? a3 : s3;
      float u0 = __shfl_xor(t2, 2), u1 = __shfl_xor(t3, 2);
      float u2 = __shfl_xor(t0, 2), u3 = __shfl_xor(t1, 2);
      bool o2 = (nn & 2);
      float w0 = o2 ? u0 : t0,  w1 = o2 ? u1 : t1;
      float w2 = o2 ? t2 : u2,  w3 = o2 ? t3 : u3;
      // lane nn now holds row kgrp*4+nn, cols (cg*16+wv*4)+0..3
      unsigned int lo = (unsigned int)f2bf(w0) | ((unsigned int)f2bf(w1) << 16);
      unsigned int hi = (unsigned int)f2bf(w2) | ((unsigned int)f2bf(w3) << 16);
      unsigned long long v = ((unsigned long long)hi << 32) | lo;
      int row = kgrp * 4 + nn;
      __hip_atomic_store(hgq + ((size_t)((t & 1) * 64 + b0 + row)) * 256 + (cg * 4 + wv), v,
                         __ATOMIC_RELAXED, __HIP_MEMORY_SCOPE_AGENT);
    }
    // ---- per-wave release: explicit vmcnt drain, then RELAXED add (no cache maintenance)
    asm volatile("s_waitcnt vmcnt(0)" ::: "memory");
    if (lane == 0)
      __hip_atomic_fetch_add(&flags[wg], 1, __ATOMIC_RELAXED, __HIP_MEMORY_SCOPE_AGENT);
  }
}

extern "C" void kernel_launch(void* const* d_in, const int* in_sizes, int n_in,
                              void* d_out, int out_size, void* d_ws, size_t ws_size,
                              hipStream_t stream){
  (void)in_sizes; (void)n_in; (void)out_size; (void)ws_size;
  const float* x  = (const float*)d_in[0];   // [64][512][512]
  const float* Wx = (const float*)d_in[1];   // [4][512][1024]
  const float* Wh = (const float*)d_in[2];   // [4][1024][1024]
  const float* b  = (const float*)d_in[3];   // [4][1024]
  char* ws = (char*)d_ws;
  unsigned short* pw    = (unsigned short*)ws;                    // 12,582,912 B packed weights
  unsigned short* xbf   = (unsigned short*)(ws + 12582912);       // 33,554,432 B x in bf16
  unsigned long long* hg= (unsigned long long*)(ws + 46137344);   //    262,144 B h double buffer
  int*            flags = (int*)(ws + 46399488);                  //      1,024 B sync counters
  float* out = (float*)d_out;

  k_convert_x<<<dim3(8192), dim3(256), 0, stream>>>(x, xbf, flags);
  k_pack_w  <<<dim3(3072), dim3(256), 0, stream>>>(Wx, Wh, pw);
  k_scan    <<<dim3(256),  dim3(256), 0, stream>>>(pw, xbf, b, (unsigned long long*)hg, flags, out);
}